// Round 7
// baseline (593.739 us; speedup 1.0000x reference)
//
#include <hip/hip_runtime.h>
#include <hip/hip_cooperative_groups.h>

namespace cg = cooperative_groups;

// RandomizedNodeLabeling — single cooperative persistent kernel, 4 phases:
//   A: xw = pack_bf16(x*w)  |  row_ptr = lower_bound(adj_row)
//   B: one_hop = A*xw, deg          (8 nodes/wave, 8 lanes/node)
//   C: two_iter = A*one_hop, degpair{deg, deg2}
//   D: per query edge: 9 fp32 dots over bf16 tables -> 15 features
// grid.sync() between phases (device-scope fence -> cross-XCD safe).
// Node vector = 64 bf16 = 128 B = 8 x uint4; lane sub owns dims sub*8..sub*8+7.

#define D 64

typedef unsigned int uint32;

__device__ __forceinline__ uint32 pack2(float a, float b) {
    // round-to-nearest-even bf16 pack: a -> lo16, b -> hi16
    uint32 ua = __float_as_uint(a);
    ua += 0x7fffu + ((ua >> 16) & 1u);
    uint32 ub = __float_as_uint(b);
    ub += 0x7fffu + ((ub >> 16) & 1u);
    return (ua >> 16) | (ub & 0xffff0000u);
}
__device__ __forceinline__ float lo2f(uint32 u) { return __uint_as_float(u << 16); }
__device__ __forceinline__ float hi2f(uint32 u) { return __uint_as_float(u & 0xffff0000u); }

#define RED_GRP(v)  { v += __shfl_xor(v, 1, 64); v += __shfl_xor(v, 2, 64);  v += __shfl_xor(v, 4, 64);  }

// ---- phase bodies -----------------------------------------------------------

template <bool WITH_DEG2>
__device__ __forceinline__ void spmm_tile(int vb, int tid,
                                          const uint4* __restrict__ src,
                                          const int* __restrict__ row_ptr,
                                          const int* __restrict__ adj_col,
                                          const float* __restrict__ degv,
                                          uint4* __restrict__ dst,
                                          float* __restrict__ degout,
                                          float2* __restrict__ degpair,
                                          int n) {
    int lane = tid & 63;
    int sub = lane & 7;
    int node = vb * 32 + (tid >> 6) * 8 + (lane >> 3);
    if (node >= n) return;
    int start = row_ptr[node], end = row_ptr[node + 1];
    int deg_n = end - start;
    float a0 = 0.f, a1 = 0.f, a2 = 0.f, a3 = 0.f,
          a4 = 0.f, a5 = 0.f, a6 = 0.f, a7 = 0.f;
    float dsum = 0.f;
    int gbase = lane & 56;                 // group's base lane for shfl
    const int* colp = adj_col + start;
    int base = 0;
    // full 8-edge blocks: trip condition is group-uniform -> maskless body
    for (; base + 8 <= deg_n; base += 8) {
        int idx = colp[base + sub];        // coalesced 8-per-group
        if (WITH_DEG2) dsum += degv[idx];
#pragma unroll
        for (int i = 0; i < 8; ++i) {
            int c = __shfl(idx, gbase + i, 64);
            uint4 qv = src[(size_t)c * 8 + sub];
            a0 += lo2f(qv.x); a1 += hi2f(qv.x);
            a2 += lo2f(qv.y); a3 += hi2f(qv.y);
            a4 += lo2f(qv.z); a5 += hi2f(qv.z);
            a6 += lo2f(qv.w); a7 += hi2f(qv.w);
        }
    }
    if (base < deg_n) {                    // tail block, exec-masked
        int k = base + sub;
        bool kv = k < deg_n;
        int idx = kv ? colp[k] : 0;
        if (WITH_DEG2) { if (kv) dsum += degv[idx]; }
#pragma unroll
        for (int i = 0; i < 8; ++i) {
            if (base + i < deg_n) {        // group-uniform predicate
                int c = __shfl(idx, gbase + i, 64);
                uint4 qv = src[(size_t)c * 8 + sub];
                a0 += lo2f(qv.x); a1 += hi2f(qv.x);
                a2 += lo2f(qv.y); a3 += hi2f(qv.y);
                a4 += lo2f(qv.z); a5 += hi2f(qv.z);
                a6 += lo2f(qv.w); a7 += hi2f(qv.w);
            }
        }
    }
    // lane owns its dims: no reduction; 8 consecutive nodes -> 1 KB contiguous store
    uint4 o;
    o.x = pack2(a0, a1); o.y = pack2(a2, a3);
    o.z = pack2(a4, a5); o.w = pack2(a6, a7);
    dst[(size_t)node * 8 + sub] = o;
    if (WITH_DEG2) {
        RED_GRP(dsum)                      // sum over the group's 8 lanes
        if (sub == 0)
            degpair[node] = make_float2((float)deg_n,
                                        fmaxf(dsum - (float)deg_n - 1.0f, 0.0f));
    } else {
        if (sub == 0) degout[node] = (float)deg_n;
    }
}

__device__ __forceinline__ void edge_tile(int vb, int tid,
                                          const int* __restrict__ edges,
                                          const uint4* __restrict__ xw,
                                          const uint4* __restrict__ h1,
                                          const uint4* __restrict__ t2,
                                          const float2* __restrict__ degpair,
                                          float* __restrict__ out,
                                          int E) {
    int t = vb * 256 + tid;
    int q = t >> 3, sub = t & 7;           // 8 lanes per edge
    if (q >= E) return;
    int u = edges[q], v = edges[E + q];
    uint4 pxu = xw[(size_t)u * 8 + sub], pxv = xw[(size_t)v * 8 + sub];
    uint4 phu = h1[(size_t)u * 8 + sub], phv = h1[(size_t)v * 8 + sub];
    uint4 ptu = t2[(size_t)u * 8 + sub], ptv = t2[(size_t)v * 8 + sub];
    float2 dpu = degpair[u], dpv = degpair[v];
    float du = dpu.x, du2 = dpu.y, dv = dpv.x, dv2 = dpv.y;

    float c11 = 0.f, c12 = 0.f, c21 = 0.f, c22 = 0.f,
          cc12 = 0.f, cc21 = 0.f, cc22 = 0.f, cs12 = 0.f, cs21 = 0.f;

    uint32 axu[4] = {pxu.x, pxu.y, pxu.z, pxu.w};
    uint32 axv[4] = {pxv.x, pxv.y, pxv.z, pxv.w};
    uint32 ahu[4] = {phu.x, phu.y, phu.z, phu.w};
    uint32 ahv[4] = {phv.x, phv.y, phv.z, phv.w};
    uint32 atu[4] = {ptu.x, ptu.y, ptu.z, ptu.w};
    uint32 atv[4] = {ptv.x, ptv.y, ptv.z, ptv.w};

    auto accum = [&](float xu, float xv, float hu, float hv, float tu, float tv) {
        float h2u = tu - hu - xu, h2v = tv - hv - xv;
        float au = fmaf(-du, xu, tu), av = fmaf(-dv, xv, tv);
        c11  = fmaf(hu,  hv,  c11);
        c12  = fmaf(hu,  h2v, c12);
        c21  = fmaf(h2u, hv,  c21);
        c22  = fmaf(h2u, h2v, c22);
        cc12 = fmaf(hu,  tv,  cc12);
        cc21 = fmaf(tu,  hv,  cc21);
        cc22 = fmaf(au,  av,  cc22);
        cs12 = fmaf(hu,  tu,  cs12);
        cs21 = fmaf(hv,  tv,  cs21);
    };
#pragma unroll
    for (int k = 0; k < 4; ++k) {
        accum(lo2f(axu[k]), lo2f(axv[k]), lo2f(ahu[k]), lo2f(ahv[k]), lo2f(atu[k]), lo2f(atv[k]));
        accum(hi2f(axu[k]), hi2f(axv[k]), hi2f(ahu[k]), hi2f(ahv[k]), hi2f(atu[k]), hi2f(atv[k]));
    }
    // reduce across the 8 lanes of this edge's group
    RED_GRP(c11) RED_GRP(c12) RED_GRP(c21) RED_GRP(c22)
    RED_GRP(cc12) RED_GRP(cc21) RED_GRP(cc22) RED_GRP(cs12) RED_GRP(cs21)

    if (sub == 0) {
        float* o = out + (size_t)q * 15;
        o[0]  = c11;
        o[1]  = c12;
        o[2]  = c21;
        o[3]  = c22;
        o[4]  = du + dv - 2.f * c11 - c12 - c21;
        o[5]  = du2 + dv2 - 2.f * c22 - c12 - c21;
        o[6]  = cc12;
        o[7]  = cc21;
        o[8]  = cc22;
        o[9]  = cs12;
        o[10] = cs21;
        o[11] = du;
        o[12] = dv;
        o[13] = du2;
        o[14] = dv2;
    }
}

// ---- fused cooperative kernel ----------------------------------------------

__global__ void __launch_bounds__(256, 8)
fused_kernel(const float4* __restrict__ x, const float* __restrict__ w,
             const int* __restrict__ edges,
             const int* __restrict__ adj_row, const int* __restrict__ adj_col,
             uint4* __restrict__ xw, uint4* __restrict__ one_hop,
             uint4* __restrict__ two_it,
             float* __restrict__ deg, float2* __restrict__ degpair,
             int* __restrict__ row_ptr, float* __restrict__ out,
             int N, int E, int NADJ) {
    cg::grid_group grid = cg::this_grid();
    const int tid = threadIdx.x;
    const int nb = gridDim.x;
    const int gstride = nb * 256;

    // Phase A: xw pack + row_ptr (grid-stride; no early return before sync!)
    {
        int n8 = N * 8;
        for (int i = blockIdx.x * 256 + tid; i < n8; i += gstride) {
            float s = w[i >> 3];
            float4 a = x[i * 2], b = x[i * 2 + 1];
            uint4 o;
            o.x = pack2(a.x * s, a.y * s);
            o.y = pack2(a.z * s, a.w * s);
            o.z = pack2(b.x * s, b.y * s);
            o.w = pack2(b.z * s, b.w * s);
            xw[i] = o;
        }
        for (int i = blockIdx.x * 256 + tid; i <= N; i += gstride) {
            int lo = 0, hi = NADJ;         // lower_bound(adj_row, i)
            while (lo < hi) {
                int mid = (lo + hi) >> 1;
                if (adj_row[mid] < i) lo = mid + 1; else hi = mid;
            }
            row_ptr[i] = lo;
        }
    }
    grid.sync();

    // Phase B: one_hop + deg
    {
        int tiles = (N + 31) / 32;
        for (int vb = blockIdx.x; vb < tiles; vb += nb)
            spmm_tile<false>(vb, tid, xw, row_ptr, adj_col, nullptr,
                             one_hop, deg, nullptr, N);
    }
    grid.sync();

    // Phase C: two_iter + degpair{deg,deg2}
    {
        int tiles = (N + 31) / 32;
        for (int vb = blockIdx.x; vb < tiles; vb += nb)
            spmm_tile<true>(vb, tid, one_hop, row_ptr, adj_col, deg,
                            two_it, nullptr, degpair, N);
    }
    grid.sync();

    // Phase D: edge features
    {
        int tiles = (int)(((size_t)E * 8 + 255) / 256);
        for (int vb = blockIdx.x; vb < tiles; vb += nb)
            edge_tile(vb, tid, edges, xw, one_hop, two_it, degpair, out, E);
    }
}

extern "C" void kernel_launch(void* const* d_in, const int* in_sizes, int n_in,
                              void* d_out, int out_size, void* d_ws, size_t ws_size,
                              hipStream_t stream) {
    const float* x       = (const float*)d_in[0];
    const float* w       = (const float*)d_in[1];
    const int*   edges   = (const int*)d_in[2];
    const int*   adj_row = (const int*)d_in[3];
    const int*   adj_col = (const int*)d_in[4];

    const int N    = in_sizes[1];        // node_weight length
    const int E    = in_sizes[2] / 2;
    const int NADJ = in_sizes[3];

    char* ws = (char*)d_ws;
    size_t off = 0;
    auto take = [&](size_t bytes) {
        void* p = ws + off;
        off = (off + bytes + 255) & ~(size_t)255;
        return p;
    };
    uint4*  xw      = (uint4*)take((size_t)N * D * 2);   // bf16 tables, 128 B/node
    uint4*  one_hop = (uint4*)take((size_t)N * D * 2);
    uint4*  two_it  = (uint4*)take((size_t)N * D * 2);
    float*  deg     = (float*)take((size_t)N * sizeof(float));
    float2* degpair = (float2*)take((size_t)N * sizeof(float2));
    int*    row_ptr = (int*)take((size_t)(N + 1) * sizeof(int));
    (void)ws_size;

    float* out = (float*)d_out;

    // co-resident grid: occupancy query x 256 CUs (gfx950), capped by phase-D demand
    int blocksPerCU = 0;
    (void)hipOccupancyMaxActiveBlocksPerMultiprocessor(&blocksPerCU,
                                                       (const void*)fused_kernel, 256, 0);
    if (blocksPerCU < 1) blocksPerCU = 1;
    long long grid = (long long)blocksPerCU * 256;
    long long maxTiles = ((long long)E * 8 + 255) / 256;
    long long tilesN = (N + 31) / 32;
    if (maxTiles < tilesN) maxTiles = tilesN;
    if (grid > maxTiles) grid = maxTiles;

    const float4* x4 = (const float4*)x;
    void* args[] = {(void*)&x4, (void*)&w, (void*)&edges, (void*)&adj_row,
                    (void*)&adj_col, (void*)&xw, (void*)&one_hop, (void*)&two_it,
                    (void*)&deg, (void*)&degpair, (void*)&row_ptr, (void*)&out,
                    (void*)&N, (void*)&E, (void*)&NADJ};
    hipLaunchCooperativeKernel((void*)fused_kernel, dim3((unsigned)grid), dim3(256),
                               args, 0, stream);
}

// Round 8
// 193.518 us; speedup vs baseline: 3.0681x; 3.0681x over previous
//
#include <hip/hip_runtime.h>

// RandomizedNodeLabeling — bf16 compact tables for spmm gathers + 384 B/node
// bundle (xw|h1|t2) for the edge phase's spatial locality.
// N=100000 nodes, D=64, NADJ=1.6M sorted-row COO, E=262144 query edges.
//
// Node vector = 64 bf16 = 128 B = 8 x uint4. Lane sub owns dims sub*8..sub*8+7.
// Compact tables (stride 8 uint4): xw, h1 — the spmm gather targets (12.8 MB each).
// Bundle (stride 24 uint4 = 384 B): [0..7]=xw [8..15]=h1 [16..23]=t2 — edge-phase
// gather target: 3 consecutive 128 B lines per endpoint instead of 3 random ones.
//
// Dispatches (4): prep(xw | row_ptr) -> spmm1 -> spmm2 -> edge.

#define D 64
#define BSTRIDE 24
#define XW_OFF 0
#define H1_OFF 8
#define T2_OFF 16

typedef unsigned int uint32;

__device__ __forceinline__ uint32 pack2(float a, float b) {
    // round-to-nearest-even bf16 pack: a -> lo16, b -> hi16
    uint32 ua = __float_as_uint(a);
    ua += 0x7fffu + ((ua >> 16) & 1u);
    uint32 ub = __float_as_uint(b);
    ub += 0x7fffu + ((ub >> 16) & 1u);
    return (ua >> 16) | (ub & 0xffff0000u);
}
__device__ __forceinline__ float lo2f(uint32 u) { return __uint_as_float(u << 16); }
__device__ __forceinline__ float hi2f(uint32 u) { return __uint_as_float(u & 0xffff0000u); }

#define RED_GRP(v)  { v += __shfl_xor(v, 1, 64); v += __shfl_xor(v, 2, 64);  v += __shfl_xor(v, 4, 64);  }

// blocks [0, xw_blocks): xw = x*w packed to bf16 (compact + bundle).
// blocks [xw_blocks, ...): row_ptr = lower_bound(adj_row).
__global__ void __launch_bounds__(256) prep_kernel(const float4* __restrict__ x,
                                                   const float* __restrict__ w,
                                                   uint4* __restrict__ xw,
                                                   uint4* __restrict__ bundle,
                                                   const int* __restrict__ adj_row,
                                                   int* __restrict__ row_ptr,
                                                   int n8, int n, int nadj, int xw_blocks) {
    if ((int)blockIdx.x < xw_blocks) {
        int i = blockIdx.x * blockDim.x + threadIdx.x;   // over n*8 uint4 groups
        if (i >= n8) return;
        int node = i >> 3, sub = i & 7;
        float s = w[node];
        float4 a = x[i * 2], b = x[i * 2 + 1];
        uint4 o;
        o.x = pack2(a.x * s, a.y * s);
        o.y = pack2(a.z * s, a.w * s);
        o.z = pack2(b.x * s, b.y * s);
        o.w = pack2(b.z * s, b.w * s);
        xw[i] = o;
        bundle[(size_t)node * BSTRIDE + XW_OFF + sub] = o;
    } else {
        int i = (blockIdx.x - xw_blocks) * blockDim.x + threadIdx.x;
        if (i > n) return;
        int lo = 0, hi = nadj;                 // lower_bound(adj_row, i)
        while (lo < hi) {
            int mid = (lo + hi) >> 1;
            if (adj_row[mid] < i) lo = mid + 1; else hi = mid;
        }
        row_ptr[i] = lo;
    }
}

// dst = A*src (src = compact table). 8 nodes per wave, 8 lanes per node.
// WITH_DEG2=false: writes compact dst + bundle H1 slot; degout[node] = degree
// WITH_DEG2=true : writes bundle T2 slot only; degpair[node] = {deg, deg2}
template <bool WITH_DEG2>
__global__ void __launch_bounds__(256) spmm_kernel(const uint4* __restrict__ src,
                                                   const int* __restrict__ row_ptr,
                                                   const int* __restrict__ adj_col,
                                                   const float* __restrict__ degv,
                                                   uint4* __restrict__ dst,      // compact (spmm1) or unused
                                                   uint4* __restrict__ bundle,   // +H1_OFF / +T2_OFF target
                                                   float* __restrict__ degout,
                                                   float2* __restrict__ degpair,
                                                   int n) {
    int lane = threadIdx.x & 63;
    int sub = lane & 7;
    int node = blockIdx.x * 32 + (threadIdx.x >> 6) * 8 + (lane >> 3);
    if (node >= n) return;
    int start = row_ptr[node], end = row_ptr[node + 1];
    int deg_n = end - start;
    float a0 = 0.f, a1 = 0.f, a2 = 0.f, a3 = 0.f,
          a4 = 0.f, a5 = 0.f, a6 = 0.f, a7 = 0.f;
    float dsum = 0.f;
    int gbase = lane & 56;                 // group's base lane for shfl
    const int* colp = adj_col + start;
    int base = 0;
    // full 8-edge blocks: trip condition is group-uniform -> maskless body
    for (; base + 8 <= deg_n; base += 8) {
        int idx = colp[base + sub];        // coalesced 8-per-group
        if (WITH_DEG2) dsum += degv[idx];
#pragma unroll
        for (int i = 0; i < 8; ++i) {
            int c = __shfl(idx, gbase + i, 64);
            uint4 qv = src[(size_t)c * 8 + sub];
            a0 += lo2f(qv.x); a1 += hi2f(qv.x);
            a2 += lo2f(qv.y); a3 += hi2f(qv.y);
            a4 += lo2f(qv.z); a5 += hi2f(qv.z);
            a6 += lo2f(qv.w); a7 += hi2f(qv.w);
        }
    }
    if (base < deg_n) {                    // tail block, exec-masked
        int k = base + sub;
        bool kv = k < deg_n;
        int idx = kv ? colp[k] : 0;
        if (WITH_DEG2) { if (kv) dsum += degv[idx]; }
#pragma unroll
        for (int i = 0; i < 8; ++i) {
            if (base + i < deg_n) {        // group-uniform predicate
                int c = __shfl(idx, gbase + i, 64);
                uint4 qv = src[(size_t)c * 8 + sub];
                a0 += lo2f(qv.x); a1 += hi2f(qv.x);
                a2 += lo2f(qv.y); a3 += hi2f(qv.y);
                a4 += lo2f(qv.z); a5 += hi2f(qv.z);
                a6 += lo2f(qv.w); a7 += hi2f(qv.w);
            }
        }
    }
    // lane owns its dims: no reduction epilogue
    uint4 o;
    o.x = pack2(a0, a1); o.y = pack2(a2, a3);
    o.z = pack2(a4, a5); o.w = pack2(a6, a7);
    if (WITH_DEG2) {
        bundle[(size_t)node * BSTRIDE + T2_OFF + sub] = o;
        RED_GRP(dsum)                      // sum over the group's 8 lanes
        if (sub == 0)
            degpair[node] = make_float2((float)deg_n,
                                        fmaxf(dsum - (float)deg_n - 1.0f, 0.0f));
    } else {
        dst[(size_t)node * 8 + sub] = o;
        bundle[(size_t)node * BSTRIDE + H1_OFF + sub] = o;
        if (sub == 0) degout[node] = (float)deg_n;
    }
}

__global__ void __launch_bounds__(256) edge_kernel(const int* __restrict__ edges, // [2,E]
                                                   const uint4* __restrict__ bundle,
                                                   const float2* __restrict__ degpair,
                                                   float* __restrict__ out,
                                                   int E) {
    int t = blockIdx.x * blockDim.x + threadIdx.x;
    int q = t >> 3, sub = t & 7;           // 8 lanes per edge
    if (q >= E) return;
    int u = edges[q], v = edges[E + q];
    const uint4* bu = bundle + (size_t)u * BSTRIDE + sub;
    const uint4* bv = bundle + (size_t)v * BSTRIDE + sub;
    uint4 pxu = bu[XW_OFF], phu = bu[H1_OFF], ptu = bu[T2_OFF];   // one 384 B block
    uint4 pxv = bv[XW_OFF], phv = bv[H1_OFF], ptv = bv[T2_OFF];
    float2 dpu = degpair[u], dpv = degpair[v];
    float du = dpu.x, du2 = dpu.y, dv = dpv.x, dv2 = dpv.y;

    float c11 = 0.f, c12 = 0.f, c21 = 0.f, c22 = 0.f,
          cc12 = 0.f, cc21 = 0.f, cc22 = 0.f, cs12 = 0.f, cs21 = 0.f;

    uint32 axu[4] = {pxu.x, pxu.y, pxu.z, pxu.w};
    uint32 axv[4] = {pxv.x, pxv.y, pxv.z, pxv.w};
    uint32 ahu[4] = {phu.x, phu.y, phu.z, phu.w};
    uint32 ahv[4] = {phv.x, phv.y, phv.z, phv.w};
    uint32 atu[4] = {ptu.x, ptu.y, ptu.z, ptu.w};
    uint32 atv[4] = {ptv.x, ptv.y, ptv.z, ptv.w};

    auto accum = [&](float xu, float xv, float hu, float hv, float tu, float tv) {
        float h2u = tu - hu - xu, h2v = tv - hv - xv;
        float au = fmaf(-du, xu, tu), av = fmaf(-dv, xv, tv);
        c11  = fmaf(hu,  hv,  c11);
        c12  = fmaf(hu,  h2v, c12);
        c21  = fmaf(h2u, hv,  c21);
        c22  = fmaf(h2u, h2v, c22);
        cc12 = fmaf(hu,  tv,  cc12);
        cc21 = fmaf(tu,  hv,  cc21);
        cc22 = fmaf(au,  av,  cc22);
        cs12 = fmaf(hu,  tu,  cs12);
        cs21 = fmaf(hv,  tv,  cs21);
    };
#pragma unroll
    for (int k = 0; k < 4; ++k) {
        accum(lo2f(axu[k]), lo2f(axv[k]), lo2f(ahu[k]), lo2f(ahv[k]), lo2f(atu[k]), lo2f(atv[k]));
        accum(hi2f(axu[k]), hi2f(axv[k]), hi2f(ahu[k]), hi2f(ahv[k]), hi2f(atu[k]), hi2f(atv[k]));
    }
    // reduce across the 8 lanes of this edge's group
    RED_GRP(c11) RED_GRP(c12) RED_GRP(c21) RED_GRP(c22)
    RED_GRP(cc12) RED_GRP(cc21) RED_GRP(cc22) RED_GRP(cs12) RED_GRP(cs21)

    if (sub == 0) {
        float* o = out + (size_t)q * 15;
        o[0]  = c11;
        o[1]  = c12;
        o[2]  = c21;
        o[3]  = c22;
        o[4]  = du + dv - 2.f * c11 - c12 - c21;
        o[5]  = du2 + dv2 - 2.f * c22 - c12 - c21;
        o[6]  = cc12;
        o[7]  = cc21;
        o[8]  = cc22;
        o[9]  = cs12;
        o[10] = cs21;
        o[11] = du;
        o[12] = dv;
        o[13] = du2;
        o[14] = dv2;
    }
}

extern "C" void kernel_launch(void* const* d_in, const int* in_sizes, int n_in,
                              void* d_out, int out_size, void* d_ws, size_t ws_size,
                              hipStream_t stream) {
    const float* x       = (const float*)d_in[0];
    const float* w       = (const float*)d_in[1];
    const int*   edges   = (const int*)d_in[2];
    const int*   adj_row = (const int*)d_in[3];
    const int*   adj_col = (const int*)d_in[4];

    const int N    = in_sizes[1];        // node_weight length
    const int E    = in_sizes[2] / 2;
    const int NADJ = in_sizes[3];

    char* ws = (char*)d_ws;
    size_t off = 0;
    auto take = [&](size_t bytes) {
        void* p = ws + off;
        off = (off + bytes + 255) & ~(size_t)255;
        return p;
    };
    uint4*  xw      = (uint4*)take((size_t)N * D * 2);                   // compact, 128 B/node
    uint4*  one_hop = (uint4*)take((size_t)N * D * 2);                   // compact
    uint4*  bundle  = (uint4*)take((size_t)N * BSTRIDE * sizeof(uint4)); // 384 B/node
    float*  deg     = (float*)take((size_t)N * sizeof(float));
    float2* degpair = (float2*)take((size_t)N * sizeof(float2));
    int*    row_ptr = (int*)take((size_t)(N + 1) * sizeof(int));
    (void)ws_size;

    float* out = (float*)d_out;

    // 1. fused: xw (compact + bundle) + CSR row pointers
    {
        int n8 = N * 8;
        int xw_blocks = (n8 + 255) / 256;
        int rp_blocks = (N + 1 + 255) / 256;
        prep_kernel<<<xw_blocks + rp_blocks, 256, 0, stream>>>(
            (const float4*)x, w, xw, bundle, adj_row, row_ptr, n8, N, NADJ, xw_blocks);
    }
    // 2. one_hop (compact + bundle) + deg   (32 nodes per 256-thread block)
    spmm_kernel<false><<<(N + 31) / 32, 256, 0, stream>>>(xw, row_ptr, adj_col, nullptr,
                                                          one_hop, bundle, deg, nullptr, N);
    // 3. two_iter (bundle only) + degpair{deg,deg2}
    spmm_kernel<true><<<(N + 31) / 32, 256, 0, stream>>>(one_hop, row_ptr, adj_col, deg,
                                                         nullptr, bundle, nullptr, degpair, N);
    // 4. edge features from bundle
    edge_kernel<<<((size_t)E * 8 + 255) / 256, 256, 0, stream>>>(edges, bundle, degpair, out, E);
}

// Round 10
// 186.191 us; speedup vs baseline: 3.1889x; 1.0394x over previous
//
#include <hip/hip_runtime.h>

// RandomizedNodeLabeling — software-fp8 xw table (64 B/node) + bf16 h1/t2.
// N=100000 nodes, D=64, NADJ=1.6M sorted-row COO, E=262144 query edges.
//
// xw stored as e4m3 of (xw*64); decode = packed bit-expand to f16 pairs with
// rebias +2 (folds the /64 back in). No fp8 hw builtins — plain bit ops.
// Byte layout per uint32: byte0=dimA byte2=dimB (even pair), byte1=dimC
// byte3=dimD (odd pair) -> two v_pk_add_f16 accumulators per word.
//
// Dispatches (4): prep(xw_fp8 | row_ptr) -> spmm1(fp8 src, f16 acc)
//                 -> spmm2(bf16 src, control arm) -> edge.

#define D 64

typedef unsigned int uint32;
typedef _Float16 h2 __attribute__((ext_vector_type(2)));

union U32H2 { uint32 u; h2 h; };
__device__ __forceinline__ h2 u_as_h2(uint32 u) { U32H2 t; t.u = u; return t.h; }

__device__ __forceinline__ uint32 pack2(float a, float b) {
    // round-to-nearest-even bf16 pack: a -> lo16, b -> hi16
    uint32 ua = __float_as_uint(a);
    ua += 0x7fffu + ((ua >> 16) & 1u);
    uint32 ub = __float_as_uint(b);
    ub += 0x7fffu + ((ub >> 16) & 1u);
    return (ua >> 16) | (ub & 0xffff0000u);
}
__device__ __forceinline__ float lo2f(uint32 u) { return __uint_as_float(u << 16); }
__device__ __forceinline__ float hi2f(uint32 u) { return __uint_as_float(u & 0xffff0000u); }

// f32 -> e4m3 byte (RNE), input pre-scaled by 64. |v| <= 64 << 448 so no inf.
__device__ __forceinline__ uint32 enc1(float v) {
    float a = fabsf(v);
    uint32 s = (__float_as_uint(v) >> 24) & 0x80u;
    if (a >= 448.f) return s | 0x7Eu;              // clamp to max normal
    if (a < 0.015625f) {                           // denormal: m = RNE(a*512)
        uint32 m = (uint32)rintf(a * 512.f);
        return (m > 7u) ? (s | 0x08u) : (s | m);
    }
    uint32 b = __float_as_uint(a);
    b += 0x7FFFFu + ((b >> 20) & 1u);              // RNE at mantissa bit 20
    uint32 m3 = (b >> 20) & 7u;
    int e4 = (int)(b >> 23) - 127 + 7;
    if (e4 > 15) return s | 0x7Eu;
    return s | ((uint32)e4 << 3) | m3;
}

// uint32 of 4 e4m3 bytes -> two packed-f16 pairs (even bytes {0,2}, odd {1,3}),
// value = e4m3 * 2^-6 (rebias +2 instead of +8 folds the unscale).
__device__ __forceinline__ void dec8(uint32 u, uint32& pe, uint32& po) {
    uint32 se = (u << 8) & 0x80008000u;
    uint32 ue = u & 0x007f007fu;
    pe = ((ue << 7) + 0x08000800u) | se;
    uint32 so = u & 0x80008000u;
    uint32 uo = (u >> 8) & 0x007f007fu;
    po = ((uo << 7) + 0x08000800u) | so;
}

#define RED_GRP(v)  { v += __shfl_xor(v, 1, 64); v += __shfl_xor(v, 2, 64);  v += __shfl_xor(v, 4, 64);  }

// blocks [0, xw_blocks): xw_fp8 = enc(x*w*64). blocks [xw_blocks, ...): row_ptr.
__global__ void __launch_bounds__(256) prep_kernel(const float4* __restrict__ x,
                                                   const float* __restrict__ w,
                                                   uint2* __restrict__ xw,
                                                   const int* __restrict__ adj_row,
                                                   int* __restrict__ row_ptr,
                                                   int n8, int n, int nadj, int xw_blocks) {
    if ((int)blockIdx.x < xw_blocks) {
        int i = blockIdx.x * blockDim.x + threadIdx.x;   // over n*8 dim-groups
        if (i >= n8) return;
        float s = w[i >> 3] * 64.f;
        float4 a = x[i * 2], b = x[i * 2 + 1];
        // word0: b0=d0 b1=d2 b2=d1 b3=d3 ; word1: b0=d4 b1=d6 b2=d5 b3=d7
        uint32 w0 = enc1(a.x * s) | (enc1(a.z * s) << 8)
                  | (enc1(a.y * s) << 16) | (enc1(a.w * s) << 24);
        uint32 w1 = enc1(b.x * s) | (enc1(b.z * s) << 8)
                  | (enc1(b.y * s) << 16) | (enc1(b.w * s) << 24);
        xw[i] = make_uint2(w0, w1);
    } else {
        int i = (blockIdx.x - xw_blocks) * blockDim.x + threadIdx.x;
        if (i > n) return;
        int lo = 0, hi = nadj;                 // lower_bound(adj_row, i)
        while (lo < hi) {
            int mid = (lo + hi) >> 1;
            if (adj_row[mid] < i) lo = mid + 1; else hi = mid;
        }
        row_ptr[i] = lo;
    }
}

// one_hop = A*xw (fp8 src, packed-f16 accumulate -> bf16 dst); deg = degree.
__global__ void __launch_bounds__(256) spmm1_kernel(const uint2* __restrict__ src,
                                                    const int* __restrict__ row_ptr,
                                                    const int* __restrict__ adj_col,
                                                    uint4* __restrict__ dst,
                                                    float* __restrict__ degout,
                                                    int n) {
    int lane = threadIdx.x & 63;
    int sub = lane & 7;
    int node = blockIdx.x * 32 + (threadIdx.x >> 6) * 8 + (lane >> 3);
    if (node >= n) return;
    int start = row_ptr[node], end = row_ptr[node + 1];
    int deg_n = end - start;
    h2 acc0 = u_as_h2(0u), acc1 = u_as_h2(0u), acc2 = u_as_h2(0u), acc3 = u_as_h2(0u);
    int gbase = lane & 56;
    const int* colp = adj_col + start;
    int base = 0;
    for (; base + 8 <= deg_n; base += 8) {     // full blocks: maskless
        int idx = colp[base + sub];
#pragma unroll
        for (int i = 0; i < 8; ++i) {
            int c = __shfl(idx, gbase + i, 64);
            uint2 qv = src[(size_t)c * 8 + sub];
            uint32 pe, po;
            dec8(qv.x, pe, po);
            acc0 += u_as_h2(pe); acc1 += u_as_h2(po);
            dec8(qv.y, pe, po);
            acc2 += u_as_h2(pe); acc3 += u_as_h2(po);
        }
    }
    if (base < deg_n) {                        // tail block, exec-masked
        int k = base + sub;
        int idx = (k < deg_n) ? colp[k] : 0;
#pragma unroll
        for (int i = 0; i < 8; ++i) {
            if (base + i < deg_n) {
                int c = __shfl(idx, gbase + i, 64);
                uint2 qv = src[(size_t)c * 8 + sub];
                uint32 pe, po;
                dec8(qv.x, pe, po);
                acc0 += u_as_h2(pe); acc1 += u_as_h2(po);
                dec8(qv.y, pe, po);
                acc2 += u_as_h2(pe); acc3 += u_as_h2(po);
            }
        }
    }
    // acc0={d0,d1} acc1={d2,d3} acc2={d4,d5} acc3={d6,d7}
    uint4 o;
    o.x = pack2((float)acc0.x, (float)acc0.y);
    o.y = pack2((float)acc1.x, (float)acc1.y);
    o.z = pack2((float)acc2.x, (float)acc2.y);
    o.w = pack2((float)acc3.x, (float)acc3.y);
    dst[(size_t)node * 8 + sub] = o;
    if (sub == 0) degout[node] = (float)deg_n;
}

// two_iter = A*one_hop (bf16 src -> bf16 dst); degpair = {deg, deg2}. (control arm)
__global__ void __launch_bounds__(256) spmm2_kernel(const uint4* __restrict__ src,
                                                    const int* __restrict__ row_ptr,
                                                    const int* __restrict__ adj_col,
                                                    const float* __restrict__ degv,
                                                    uint4* __restrict__ dst,
                                                    float2* __restrict__ degpair,
                                                    int n) {
    int lane = threadIdx.x & 63;
    int sub = lane & 7;
    int node = blockIdx.x * 32 + (threadIdx.x >> 6) * 8 + (lane >> 3);
    if (node >= n) return;
    int start = row_ptr[node], end = row_ptr[node + 1];
    int deg_n = end - start;
    float a0 = 0.f, a1 = 0.f, a2 = 0.f, a3 = 0.f,
          a4 = 0.f, a5 = 0.f, a6 = 0.f, a7 = 0.f;
    float dsum = 0.f;
    int gbase = lane & 56;
    const int* colp = adj_col + start;
    int base = 0;
    for (; base + 8 <= deg_n; base += 8) {
        int idx = colp[base + sub];
        dsum += degv[idx];
#pragma unroll
        for (int i = 0; i < 8; ++i) {
            int c = __shfl(idx, gbase + i, 64);
            uint4 qv = src[(size_t)c * 8 + sub];
            a0 += lo2f(qv.x); a1 += hi2f(qv.x);
            a2 += lo2f(qv.y); a3 += hi2f(qv.y);
            a4 += lo2f(qv.z); a5 += hi2f(qv.z);
            a6 += lo2f(qv.w); a7 += hi2f(qv.w);
        }
    }
    if (base < deg_n) {
        int k = base + sub;
        bool kv = k < deg_n;
        int idx = kv ? colp[k] : 0;
        if (kv) dsum += degv[idx];
#pragma unroll
        for (int i = 0; i < 8; ++i) {
            if (base + i < deg_n) {
                int c = __shfl(idx, gbase + i, 64);
                uint4 qv = src[(size_t)c * 8 + sub];
                a0 += lo2f(qv.x); a1 += hi2f(qv.x);
                a2 += lo2f(qv.y); a3 += hi2f(qv.y);
                a4 += lo2f(qv.z); a5 += hi2f(qv.z);
                a6 += lo2f(qv.w); a7 += hi2f(qv.w);
            }
        }
    }
    uint4 o;
    o.x = pack2(a0, a1); o.y = pack2(a2, a3);
    o.z = pack2(a4, a5); o.w = pack2(a6, a7);
    dst[(size_t)node * 8 + sub] = o;
    RED_GRP(dsum)                              // sum over the group's 8 lanes
    if (sub == 0)
        degpair[node] = make_float2((float)deg_n,
                                    fmaxf(dsum - (float)deg_n - 1.0f, 0.0f));
}

__global__ void __launch_bounds__(256) edge_kernel(const int* __restrict__ edges, // [2,E]
                                                   const uint2* __restrict__ xw,
                                                   const uint4* __restrict__ h1,
                                                   const uint4* __restrict__ t2,
                                                   const float2* __restrict__ degpair,
                                                   float* __restrict__ out,
                                                   int E) {
    int t = blockIdx.x * blockDim.x + threadIdx.x;
    int q = t >> 3, sub = t & 7;           // 8 lanes per edge
    if (q >= E) return;
    int u = edges[q], v = edges[E + q];
    uint2 pxu = xw[(size_t)u * 8 + sub], pxv = xw[(size_t)v * 8 + sub];
    uint4 phu = h1[(size_t)u * 8 + sub], phv = h1[(size_t)v * 8 + sub];
    uint4 ptu = t2[(size_t)u * 8 + sub], ptv = t2[(size_t)v * 8 + sub];
    float2 dpu = degpair[u], dpv = degpair[v];
    float du = dpu.x, du2 = dpu.y, dv = dpv.x, dv2 = dpv.y;

    float fxu[8], fxv[8], fhu[8], fhv[8], ftu[8], ftv[8];
    {
        uint32 pe, po;
        dec8(pxu.x, pe, po);
        h2 e = u_as_h2(pe), o_ = u_as_h2(po);
        fxu[0] = (float)e.x; fxu[1] = (float)e.y; fxu[2] = (float)o_.x; fxu[3] = (float)o_.y;
        dec8(pxu.y, pe, po);
        e = u_as_h2(pe); o_ = u_as_h2(po);
        fxu[4] = (float)e.x; fxu[5] = (float)e.y; fxu[6] = (float)o_.x; fxu[7] = (float)o_.y;
        dec8(pxv.x, pe, po);
        e = u_as_h2(pe); o_ = u_as_h2(po);
        fxv[0] = (float)e.x; fxv[1] = (float)e.y; fxv[2] = (float)o_.x; fxv[3] = (float)o_.y;
        dec8(pxv.y, pe, po);
        e = u_as_h2(pe); o_ = u_as_h2(po);
        fxv[4] = (float)e.x; fxv[5] = (float)e.y; fxv[6] = (float)o_.x; fxv[7] = (float)o_.y;
    }
    fhu[0]=lo2f(phu.x); fhu[1]=hi2f(phu.x); fhu[2]=lo2f(phu.y); fhu[3]=hi2f(phu.y);
    fhu[4]=lo2f(phu.z); fhu[5]=hi2f(phu.z); fhu[6]=lo2f(phu.w); fhu[7]=hi2f(phu.w);
    fhv[0]=lo2f(phv.x); fhv[1]=hi2f(phv.x); fhv[2]=lo2f(phv.y); fhv[3]=hi2f(phv.y);
    fhv[4]=lo2f(phv.z); fhv[5]=hi2f(phv.z); fhv[6]=lo2f(phv.w); fhv[7]=hi2f(phv.w);
    ftu[0]=lo2f(ptu.x); ftu[1]=hi2f(ptu.x); ftu[2]=lo2f(ptu.y); ftu[3]=hi2f(ptu.y);
    ftu[4]=lo2f(ptu.z); ftu[5]=hi2f(ptu.z); ftu[6]=lo2f(ptu.w); ftu[7]=hi2f(ptu.w);
    ftv[0]=lo2f(ptv.x); ftv[1]=hi2f(ptv.x); ftv[2]=lo2f(ptv.y); ftv[3]=hi2f(ptv.y);
    ftv[4]=lo2f(ptv.z); ftv[5]=hi2f(ptv.z); ftv[6]=lo2f(ptv.w); ftv[7]=hi2f(ptv.w);

    float c11 = 0.f, c12 = 0.f, c21 = 0.f, c22 = 0.f,
          cc12 = 0.f, cc21 = 0.f, cc22 = 0.f, cs12 = 0.f, cs21 = 0.f;
#pragma unroll
    for (int j = 0; j < 8; ++j) {
        float xu = fxu[j], xv = fxv[j];
        float hu = fhu[j], hv = fhv[j];
        float tu = ftu[j], tv = ftv[j];
        float h2u = tu - hu - xu, h2v = tv - hv - xv;
        float au = fmaf(-du, xu, tu), av = fmaf(-dv, xv, tv);
        c11  = fmaf(hu,  hv,  c11);
        c12  = fmaf(hu,  h2v, c12);
        c21  = fmaf(h2u, hv,  c21);
        c22  = fmaf(h2u, h2v, c22);
        cc12 = fmaf(hu,  tv,  cc12);
        cc21 = fmaf(tu,  hv,  cc21);
        cc22 = fmaf(au,  av,  cc22);
        cs12 = fmaf(hu,  tu,  cs12);
        cs21 = fmaf(hv,  tv,  cs21);
    }
    RED_GRP(c11) RED_GRP(c12) RED_GRP(c21) RED_GRP(c22)
    RED_GRP(cc12) RED_GRP(cc21) RED_GRP(cc22) RED_GRP(cs12) RED_GRP(cs21)

    if (sub == 0) {
        float* o = out + (size_t)q * 15;
        o[0]  = c11;
        o[1]  = c12;
        o[2]  = c21;
        o[3]  = c22;
        o[4]  = du + dv - 2.f * c11 - c12 - c21;
        o[5]  = du2 + dv2 - 2.f * c22 - c12 - c21;
        o[6]  = cc12;
        o[7]  = cc21;
        o[8]  = cc22;
        o[9]  = cs12;
        o[10] = cs21;
        o[11] = du;
        o[12] = dv;
        o[13] = du2;
        o[14] = dv2;
    }
}

extern "C" void kernel_launch(void* const* d_in, const int* in_sizes, int n_in,
                              void* d_out, int out_size, void* d_ws, size_t ws_size,
                              hipStream_t stream) {
    const float* x       = (const float*)d_in[0];
    const float* w       = (const float*)d_in[1];
    const int*   edges   = (const int*)d_in[2];
    const int*   adj_row = (const int*)d_in[3];
    const int*   adj_col = (const int*)d_in[4];

    const int N    = in_sizes[1];        // node_weight length
    const int E    = in_sizes[2] / 2;
    const int NADJ = in_sizes[3];

    char* ws = (char*)d_ws;
    size_t off = 0;
    auto take = [&](size_t bytes) {
        void* p = ws + off;
        off = (off + bytes + 255) & ~(size_t)255;
        return p;
    };
    uint2*  xw      = (uint2*)take((size_t)N * 8 * sizeof(uint2));  // fp8: 64 B/node
    uint4*  one_hop = (uint4*)take((size_t)N * D * 2);              // bf16: 128 B/node
    uint4*  two_it  = (uint4*)take((size_t)N * D * 2);
    float*  deg     = (float*)take((size_t)N * sizeof(float));
    float2* degpair = (float2*)take((size_t)N * sizeof(float2));
    int*    row_ptr = (int*)take((size_t)(N + 1) * sizeof(int));
    (void)ws_size;

    float* out = (float*)d_out;

    // 1. fused: xw fp8 encode + CSR row pointers
    {
        int n8 = N * 8;
        int xw_blocks = (n8 + 255) / 256;
        int rp_blocks = (N + 1 + 255) / 256;
        prep_kernel<<<xw_blocks + rp_blocks, 256, 0, stream>>>(
            (const float4*)x, w, xw, adj_row, row_ptr, n8, N, NADJ, xw_blocks);
    }
    // 2. one_hop + deg   (32 nodes per 256-thread block)
    spmm1_kernel<<<(N + 31) / 32, 256, 0, stream>>>(xw, row_ptr, adj_col, one_hop, deg, N);
    // 3. two_iter + degpair{deg,deg2}
    spmm2_kernel<<<(N + 31) / 32, 256, 0, stream>>>(one_hop, row_ptr, adj_col, deg,
                                                    two_it, degpair, N);
    // 4. edge features
    edge_kernel<<<((size_t)E * 8 + 255) / 256, 256, 0, stream>>>(edges, xw, one_hop, two_it,
                                                                 degpair, out, E);
}